// Round 1
// baseline (458.177 us; speedup 1.0000x reference)
//
#include <hip/hip_runtime.h>

#define TDIM 256
#define BM 128
#define BK 32
#define LDST 40   // LDS row stride in bf16 elements (80 B, keeps ds_read_b128 aligned, breaks bank conflicts)

typedef __attribute__((ext_vector_type(4))) float f32x4;
typedef __attribute__((ext_vector_type(8))) short s16x8;

__device__ __forceinline__ unsigned short f2bf(float f) {
    union { float f; unsigned int u; } c; c.f = f;
    unsigned int u = c.u;
    u += 0x7fffu + ((u >> 16) & 1u);   // round-to-nearest-even
    return (unsigned short)(u >> 16);
}

// X: (M=262144, 256) row-major fp32; W: (256,256) row-major fp32 (row i = weights over j);
// bias: (256,) fp32; out: (M, 256) row-major fp32.
// Block computes BM x 256 output tile. Grid = M/BM = 2048.
__global__ __launch_bounds__(256, 2)
void triu_gemm_kernel(const float* __restrict__ X, const float* __restrict__ W,
                      const float* __restrict__ bias, float* __restrict__ out) {
    __shared__ __align__(16) unsigned short As[BM * LDST];    // 10240 B
    __shared__ __align__(16) unsigned short Bs[TDIM * LDST];  // 20480 B

    const int tid  = threadIdx.x;
    const int wave = tid >> 6;
    const int lane = tid & 63;
    const int quad = lane >> 4;
    const int l16  = lane & 15;
    const int wm   = wave & 1;    // 64-row slice within block tile
    const int wn   = wave >> 1;   // 128-col slice

    const long m0 = (long)blockIdx.x * BM;

    f32x4 acc[4][8];
#pragma unroll
    for (int i = 0; i < 4; ++i)
#pragma unroll
        for (int j = 0; j < 8; ++j)
            acc[i][j] = (f32x4){0.f, 0.f, 0.f, 0.f};

    const int rr = tid >> 2;        // 0..63
    const int kq = (tid & 3) * 8;   // 0,8,16,24

    for (int k0 = 0; k0 < TDIM; k0 += BK) {
        // ---- stage A: x tile (BM x BK) fp32 -> bf16 ----
#pragma unroll
        for (int p = 0; p < 2; ++p) {
            const int row = p * 64 + rr;
            const float* src = X + (m0 + row) * TDIM + (k0 + kq);
            f32x4 v0 = *(const f32x4*)src;
            f32x4 v1 = *(const f32x4*)(src + 4);
            s16x8 sv;
            sv[0] = (short)f2bf(v0[0]); sv[1] = (short)f2bf(v0[1]);
            sv[2] = (short)f2bf(v0[2]); sv[3] = (short)f2bf(v0[3]);
            sv[4] = (short)f2bf(v1[0]); sv[5] = (short)f2bf(v1[1]);
            sv[6] = (short)f2bf(v1[2]); sv[7] = (short)f2bf(v1[3]);
            *(s16x8*)&As[row * LDST + kq] = sv;
        }
        // ---- stage B: masked W tile (256 x BK), B_lds[n][k] = (k<=n) ? W[n][k] : 0 ----
#pragma unroll
        for (int p = 0; p < 4; ++p) {
            const int n = p * 64 + rr;
            const float* src = W + n * TDIM + (k0 + kq);
            f32x4 v0 = *(const f32x4*)src;
            f32x4 v1 = *(const f32x4*)(src + 4);
            float t[8] = {v0[0], v0[1], v0[2], v0[3], v1[0], v1[1], v1[2], v1[3]};
            s16x8 sv;
#pragma unroll
            for (int e = 0; e < 8; ++e) {
                const int j = k0 + kq + e;
                sv[e] = (short)f2bf(j <= n ? t[e] : 0.0f);
            }
            *(s16x8*)&Bs[n * LDST + kq] = sv;
        }
        __syncthreads();

        // ---- fragments + MFMA ----
        s16x8 af[4], bfr[8];
#pragma unroll
        for (int mi = 0; mi < 4; ++mi)
            af[mi] = *(const s16x8*)&As[(wm * 64 + mi * 16 + l16) * LDST + quad * 8];
#pragma unroll
        for (int ni = 0; ni < 8; ++ni)
            bfr[ni] = *(const s16x8*)&Bs[(wn * 128 + ni * 16 + l16) * LDST + quad * 8];

#pragma unroll
        for (int mi = 0; mi < 4; ++mi)
#pragma unroll
            for (int ni = 0; ni < 8; ++ni)
                acc[mi][ni] = __builtin_amdgcn_mfma_f32_16x16x32_bf16(
                    af[mi], bfr[ni], acc[mi][ni], 0, 0, 0);
        __syncthreads();
    }

    // ---- epilogue: bias add + store. C/D layout: col = lane&15, row = quad*4 + reg ----
#pragma unroll
    for (int ni = 0; ni < 8; ++ni) {
        const int n = wn * 128 + ni * 16 + l16;
        const float bv = bias[n];
#pragma unroll
        for (int mi = 0; mi < 4; ++mi) {
            const long mb = m0 + wm * 64 + mi * 16 + quad * 4;
            float* dst = out + mb * TDIM + n;
#pragma unroll
            for (int r = 0; r < 4; ++r)
                dst[(long)r * TDIM] = acc[mi][ni][r] + bv;
        }
    }
}

extern "C" void kernel_launch(void* const* d_in, const int* in_sizes, int n_in,
                              void* d_out, int out_size, void* d_ws, size_t ws_size,
                              hipStream_t stream) {
    const float* X    = (const float*)d_in[0];   // (256,1024,256) = (M=262144, 256)
    const float* W    = (const float*)d_in[1];   // (256,256)
    const float* bias = (const float*)d_in[2];   // (256,)
    float* out        = (float*)d_out;           // (M, 256)

    const int M = 256 * 1024;                    // B*C
    dim3 grid(M / BM);                           // 2048 blocks
    dim3 block(256);
    triu_gemm_kernel<<<grid, block, 0, stream>>>(X, W, bias, out);
}